// Round 8
// baseline (327.382 us; speedup 1.0000x reference)
//
#include <hip/hip_runtime.h>

#define B_ 4
#define T_ 4096
#define C_ 2048
#define HD_ 128
#define M_ (B_*T_)   // 16384 rows total

typedef __bf16 bf8 __attribute__((ext_vector_type(8)));
typedef __bf16 bf16x2 __attribute__((ext_vector_type(2)));
typedef __bf16 bf16x4 __attribute__((ext_vector_type(4)));
typedef unsigned short u16x8 __attribute__((ext_vector_type(8)));
typedef unsigned short u16x4 __attribute__((ext_vector_type(4)));
typedef float f32x4 __attribute__((ext_vector_type(4)));

typedef __attribute__((address_space(3))) unsigned char lds_u8_t;
typedef __attribute__((address_space(1))) const unsigned char gm_u8_t;

// async global->LDS, 16B per lane; LDS dest = wave-uniform base + lane*16
__device__ __forceinline__ void glds16(const void* g, void* l) {
    __builtin_amdgcn_global_load_lds((gm_u8_t*)g, (lds_u8_t*)l, 16, 0, 0);
}

// hardware bf16 conversion (gfx950: v_cvt_pk_bf16_f32), RNE
__device__ __forceinline__ bf8 cvt_bf8(float4 a, float4 b) {
    bf8 t;
    t[0]=(__bf16)a.x; t[1]=(__bf16)a.y; t[2]=(__bf16)a.z; t[3]=(__bf16)a.w;
    t[4]=(__bf16)b.x; t[5]=(__bf16)b.y; t[6]=(__bf16)b.z; t[7]=(__bf16)b.w;
    return t;
}
__device__ __forceinline__ unsigned pk2(float a, float b) {
    bf16x2 t; t[0] = (__bf16)a; t[1] = (__bf16)b;
    return __builtin_bit_cast(unsigned, t);
}
__device__ __forceinline__ u16x4 pk4(float a, float b, float c, float d) {
    bf16x4 t; t[0]=(__bf16)a; t[1]=(__bf16)b; t[2]=(__bf16)c; t[3]=(__bf16)d;
    return __builtin_bit_cast(u16x4, t);
}
__device__ __forceinline__ bf8 ld_bf8(const unsigned short* p) {
    u16x8 t = *(const u16x8*)p;
    return __builtin_bit_cast(bf8, t);
}
__device__ __forceinline__ float bf2f(unsigned short h) {
    unsigned u = ((unsigned)h) << 16;
    return __builtin_bit_cast(float, u);
}
__device__ __forceinline__ f32x4 zero4() { f32x4 v = {0.f,0.f,0.f,0.f}; return v; }

// ---------------------------------------------------------------------------
// Kernel 0: convert Wq|Wk|Wv (fp32) -> wbf (bf16), contiguous [3][128][2048]
// ---------------------------------------------------------------------------
__global__ __launch_bounds__(256) void wconv(
    const float* __restrict__ Wq, const float* __restrict__ Wk,
    const float* __restrict__ Wv, unsigned short* __restrict__ wbf)
{
    int idx = blockIdx.x * 256 + threadIdx.x;   // 0..98303
    int e = idx * 8;
    int z = e >> 18;                            // 128*2048 = 262144 = 2^18
    int r = e & 262143;
    const float* src = (z == 0 ? Wq : z == 1 ? Wk : Wv) + r;
    float4 a = *(const float4*)src;
    float4 b = *(const float4*)(src + 4);
    bf8 o = cvt_bf8(a, b);
    *(u16x8*)(wbf + e) = __builtin_bit_cast(u16x8, o);
}

// ---------------------------------------------------------------------------
// Kernel 1: per-matrix GEMM (x @ Wz^T) + RoPE epilogue.
// r7 shell (64-row tiles, grid 768, XCD-aware decode, HW bf16 casts) with
// DOUBLE-BUFFERED staging, ONE barrier per K-iter: stage(t+1) issued right
// after the barrier publishing tile t -> by the next barrier those loads are
// one compute-phase old, drain ~0. LDS 64 KB -> 2 blocks/CU.
// ---------------------------------------------------------------------------
__global__ __launch_bounds__(256) void qkv_gemm(
    const float* __restrict__ x, const unsigned short* __restrict__ wbf,
    const float* __restrict__ cosp, const float* __restrict__ sinp,
    unsigned short* __restrict__ qws, unsigned short* __restrict__ kws,
    unsigned short* __restrict__ vws)
{
    __shared__ __align__(16) float xs[2][64*64];            // 32 KB
    __shared__ __align__(16) unsigned short ws2[2][128*64]; // 32 KB

    const int tid = threadIdx.x;
    const int w = tid >> 6, l = tid & 63;
    const int g = blockIdx.x;
    const int xcd = g & 7;
    const int s = g >> 3;            // 0..95
    const int z = s % 3;
    const int mm = s / 3;            // 0..31
    const int mt = mm * 8 + xcd;
    const int rowbase = mt * 64;

    const int swz = l & 7;
    const int aq  = l >> 4;
    const int coll = l & 15;

    f32x4 acc[2][4];
    #pragma unroll
    for (int i = 0; i < 2; ++i)
        #pragma unroll
        for (int j = 0; j < 4; ++j) acc[i][j] = zero4();

    const unsigned short* wsrc = wbf + (size_t)z * (HD_ * C_);

    auto stage = [&](int buf, int kc) {
        #pragma unroll
        for (int c = 0; c < 4; ++c) {            // x: 64 rows x 64 f32
            int row = w * 16 + c * 4 + aq;
            int fb = coll ^ (row & 7);
            glds16(x + (size_t)(rowbase + row) * C_ + kc + fb * 4,
                   (void*)&xs[buf][(w * 16 + c * 4) * 64]);
        }
        #pragma unroll
        for (int c = 0; c < 4; ++c) {            // W: 128 rows x 64 bf16
            int row = w * 32 + c * 8 + (l >> 3);
            int fb = (l & 7) ^ (row & 7);
            glds16(wsrc + (size_t)row * C_ + kc + fb * 8,
                   (void*)&ws2[buf][(w * 32 + c * 8) * 64]);
        }
    };

    stage(0, 0);

    for (int it = 0; it < 32; ++it) {
        __syncthreads();                          // publishes buf it; prior reads done
        if (it + 1 < 32) stage((it + 1) & 1, (it + 1) * 64);
        const float* xcur = xs[it & 1];
        const unsigned short* wcur = ws2[it & 1];

        #pragma unroll
        for (int ks_ = 0; ks_ < 2; ++ks_) {
            bf8 a[2];
            #pragma unroll
            for (int mi = 0; mi < 2; ++mi) {
                int row = (w & 1) * 32 + mi * 16 + coll;   // row&7 == swz
                int s0 = ks_ * 8 + aq * 2;
                float4 fa = *(const float4*)&xcur[row * 64 + ((s0 ^ swz) << 2)];
                float4 fb = *(const float4*)&xcur[row * 64 + (((s0 + 1) ^ swz) << 2)];
                a[mi] = cvt_bf8(fa, fb);                   // HW v_cvt_pk_bf16_f32
            }
            #pragma unroll
            for (int nt = 0; nt < 4; ++nt) {
                int row = (w >> 1) * 64 + nt * 16 + coll;  // row&7 == swz
                int slot = (ks_ * 4 + aq) ^ swz;
                bf8 bb = ld_bf8(&wcur[row * 64 + (slot << 3)]);
                acc[0][nt] = __builtin_amdgcn_mfma_f32_16x16x32_bf16(a[0], bb, acc[0][nt], 0, 0, 0);
                acc[1][nt] = __builtin_amdgcn_mfma_f32_16x16x32_bf16(a[1], bb, acc[1][nt], 0, 0, 0);
            }
        }
    }

    // epilogue
    const int rl0 = aq * 4;
    const int cbase = (w >> 1) * 64;
    const int mrow = (w & 1) * 32;
    if (z < 2) {
        const float QSC = 0.022097086912079608f * 1.44269504088896340736f;
        const float fs = (z == 0) ? QSC : 1.0f;
        unsigned short* dst = (z == 0) ? qws : kws;
        #pragma unroll
        for (int mi = 0; mi < 2; ++mi) {
            #pragma unroll
            for (int nt = 0; nt < 4; ++nt) {
                int col = cbase + nt * 16 + coll;
                #pragma unroll
                for (int r = 0; r < 4; ++r) {
                    float val = acc[mi][nt][r];
                    float oth = __shfl_xor(val, 1, 64);
                    int grow = rowbase + mrow + mi * 16 + rl0 + r;
                    int t = grow & (T_ - 1);
                    if ((coll & 1) == 0) {
                        int i = col >> 1;
                        float cv = cosp[t * 64 + i], sv = sinp[t * 64 + i];
                        float o_r = (val * cv - oth * sv) * fs;
                        float o_i = (val * sv + oth * cv) * fs;
                        *(unsigned*)&dst[(size_t)grow * HD_ + col] = pk2(o_r, o_i);
                    }
                }
            }
        }
    } else {
        const int bq = rowbase >> 12;
        #pragma unroll
        for (int mi = 0; mi < 2; ++mi) {
            int tb = (rowbase + mrow + mi * 16 + rl0) & (T_ - 1);
            #pragma unroll
            for (int nt = 0; nt < 4; ++nt) {
                int col = cbase + nt * 16 + coll;
                u16x4 pk = pk4(acc[mi][nt][0], acc[mi][nt][1], acc[mi][nt][2], acc[mi][nt][3]);
                *(u16x4*)&vws[(size_t)(bq * HD_ + col) * T_ + tb] = pk;  // transposed
            }
        }
    }
}

// ---------------------------------------------------------------------------
// Kernel 2a: split-K causal flash attention, phase 1.
// Grid 1152 = 4 b x 288 jobs (<=8 K-tiles each, r4's proven decode).
// 64-row Q tiles; wave owns 16 rows x all 64 S-cols -> wave-private P ->
// ONE barrier/iter. K/V double-buffered glds16, issue-after-barrier.
// Q held in REGISTERS (no qs) -> LDS 73 KB -> 2 blocks/CU.
// Fixed-max softmax (max==0): partials share the max -> merge = plain sums.
// ---------------------------------------------------------------------------
__global__ __launch_bounds__(256) void attn_part(
    const unsigned short* __restrict__ qws, const unsigned short* __restrict__ kws,
    const unsigned short* __restrict__ vws,
    unsigned short* __restrict__ partO, float* __restrict__ partL)
{
    __shared__ __align__(16) unsigned short ks[2][64*128];   // 32 KB
    __shared__ __align__(16) unsigned short vs[2][128*64];   // 32 KB
    __shared__ __align__(16) unsigned short ps[4*16*72];     //  9 KB (per-wave P)

    const int tid = threadIdx.x;
    const int w = tid >> 6, l = tid & 63;
    // r4 decode: XCD-paired b, heavy (8-tile) jobs first
    const int id = blockIdx.x;
    const int xcd = id & 7;
    const int b = xcd >> 1;
    const int j = (id >> 3) * 2 + (xcd & 1);    // 0..287
    const int sp = 287 - j;
    int g = 0;
    while (4 * (g + 1) * (g + 2) <= sp) ++g;
    const int r_ = sp - 4 * g * (g + 1);
    const int qdiv = r_ / (g + 1);
    const int qt = 8 * g + qdiv;                // 0..63
    const int c  = r_ - qdiv * (g + 1);         // chunk 0..g
    const int ntiles = (c < g) ? 8 : ((qt & 7) + 1);
    const int slot = b * 288 + 4 * g * (g + 1) + (qt & 7) * (g + 1) + c;
    const int qbase = qt * 64;
    const int cbase = c * 512;
    const size_t rowoff = (size_t)b * T_;

    const int swz = l & 7, aq = l >> 4, coll = l & 15;
    unsigned short* psw = ps + w * (16 * 72);

    // Q A-fragments in registers: A[m=coll][k = kk*32 + aq*8 + jj]
    bf8 qf[4];
    {
        const unsigned short* qp = qws + (rowoff + qbase + w * 16 + coll) * HD_ + aq * 8;
        #pragma unroll
        for (int kk = 0; kk < 4; ++kk) qf[kk] = ld_bf8(qp + kk * 32);
    }

    auto stageKV = [&](int buf, int st) {
        const int sbase = cbase + st * 64;
        #pragma unroll
        for (int cc = 0; cc < 4; ++cc) {              // K: 64 rows x 128
            int row = w * 16 + cc * 4 + aq;
            int fb = coll ^ (row & 7);
            glds16(kws + (rowoff + sbase + row) * HD_ + fb * 8,
                   (void*)&ks[buf][(w * 16 + cc * 4) * 128]);
        }
        #pragma unroll
        for (int cc = 0; cc < 4; ++cc) {              // V: 128 d-rows x 64 s
            int row = w * 32 + cc * 8 + (l >> 3);
            int fb = (l & 7) ^ (row & 7);
            glds16(vws + ((size_t)(b * HD_ + row)) * T_ + sbase + fb * 8,
                   (void*)&vs[buf][(w * 32 + cc * 8) * 64]);
        }
    };
    stageKV(0, 0);

    float l_r[4] = {0.f, 0.f, 0.f, 0.f};
    f32x4 accO[8];
    #pragma unroll
    for (int i = 0; i < 8; ++i) accO[i] = zero4();

    for (int st = 0; st < ntiles; ++st) {
        __syncthreads();                              // publishes buf st; prior reads done
        if (st + 1 < ntiles) stageKV((st + 1) & 1, st + 1);
        const unsigned short* kcur = ks[st & 1];
        const unsigned short* vcur = vs[st & 1];
        const int sbase = cbase + st * 64;
        const bool masked = (sbase == qbase);         // only last tile of last chunk

        // S = Q K^T (wave: its 16 rows x 64 cols), Q from registers
        f32x4 sacc[4];
        #pragma unroll
        for (int i = 0; i < 4; ++i) sacc[i] = zero4();
        #pragma unroll
        for (int kk = 0; kk < 4; ++kk) {
            const int slot8 = ((kk * 4 + aq) ^ swz) << 3;
            #pragma unroll
            for (int nt = 0; nt < 4; ++nt) {
                bf8 bb = ld_bf8(&kcur[(nt * 16 + coll) * 128 + slot8]);
                sacc[nt] = __builtin_amdgcn_mfma_f32_16x16x32_bf16(qf[kk], bb, sacc[nt], 0, 0, 0);
            }
        }

        // fixed-max softmax: p = exp2(s); wave-private ps; lane-local l
        #pragma unroll
        for (int r = 0; r < 4; ++r) {
            float s0 = sacc[0][r], s1 = sacc[1][r], s2 = sacc[2][r], s3 = sacc[3][r];
            if (masked) {
                int qi = qbase + w * 16 + aq * 4 + r;
                int ki = sbase + coll;
                s0 = (ki      > qi) ? -1e30f : s0;
                s1 = (ki + 16 > qi) ? -1e30f : s1;
                s2 = (ki + 32 > qi) ? -1e30f : s2;
                s3 = (ki + 48 > qi) ? -1e30f : s3;
            }
            float p0 = __builtin_amdgcn_exp2f(s0);
            float p1 = __builtin_amdgcn_exp2f(s1);
            float p2 = __builtin_amdgcn_exp2f(s2);
            float p3 = __builtin_amdgcn_exp2f(s3);
            __bf16 c0 = (__bf16)p0, c1 = (__bf16)p1, c2 = (__bf16)p2, c3 = (__bf16)p3;
            const int prow = (aq * 4 + r) * 72;
            psw[prow + coll]      = __builtin_bit_cast(unsigned short, c0);
            psw[prow + 16 + coll] = __builtin_bit_cast(unsigned short, c1);
            psw[prow + 32 + coll] = __builtin_bit_cast(unsigned short, c2);
            psw[prow + 48 + coll] = __builtin_bit_cast(unsigned short, c3);
            l_r[r] += ((float)c0 + (float)c1) + ((float)c2 + (float)c3);
        }
        // no barrier: ps is wave-private (same-wave lgkm ordering)

        // O += P V (wave: 16 rows x 128 O-cols)
        #pragma unroll
        for (int kk = 0; kk < 2; ++kk) {
            bf8 a = ld_bf8(&psw[coll * 72 + kk * 32 + aq * 8]);
            const int slot8 = ((kk * 4 + aq) ^ swz) << 3;
            #pragma unroll
            for (int nt = 0; nt < 8; ++nt) {
                bf8 bb = ld_bf8(&vcur[(nt * 16 + coll) * 64 + slot8]);
                accO[nt] = __builtin_amdgcn_mfma_f32_16x16x32_bf16(a, bb, accO[nt], 0, 0, 0);
            }
        }
    }

    // epilogue: unnormalized bf16 O + fp32 l per row (shared max==0)
    unsigned short* op = partO + (size_t)slot * (64 * 128);
    #pragma unroll
    for (int r = 0; r < 4; ++r) {
        float s = l_r[r];
        s += __shfl_xor(s, 1, 64);
        s += __shfl_xor(s, 2, 64);
        s += __shfl_xor(s, 4, 64);
        s += __shfl_xor(s, 8, 64);
        int row = w * 16 + aq * 4 + r;
        #pragma unroll
        for (int nt = 0; nt < 8; ++nt) {
            __bf16 ob = (__bf16)accO[nt][r];
            op[row * 128 + nt * 16 + coll] = __builtin_bit_cast(unsigned short, ob);
        }
        if (coll == 0) partL[slot * 64 + row] = s;
    }
}

// ---------------------------------------------------------------------------
// Kernel 2b: merge partials (plain sums — shared fixed max). Grid 256 =
// (b,qt); thread owns one (row, 32-col group).
// ---------------------------------------------------------------------------
__global__ __launch_bounds__(256) void attn_merge(
    const unsigned short* __restrict__ partO, const float* __restrict__ partL,
    float* __restrict__ out)
{
    const int bq = blockIdx.x;
    const int b = bq >> 6, qt = bq & 63;
    const int g = qt >> 3;
    const int nc = g + 1;
    const int slotbase = b * 288 + 4 * g * (g + 1) + (qt & 7) * (g + 1);
    const int row = threadIdx.x >> 2;
    const int cg = (threadIdx.x & 3) * 32;

    float acc[32];
    #pragma unroll
    for (int e = 0; e < 32; ++e) acc[e] = 0.f;
    float L = 0.f;
    for (int c = 0; c < nc; ++c) {
        const int slot = slotbase + c;
        L += partL[slot * 64 + row];
        const unsigned short* op = partO + (size_t)slot * (64 * 128) + row * 128 + cg;
        #pragma unroll
        for (int k = 0; k < 4; ++k) {
            u16x8 t = *(const u16x8*)(op + k * 8);
            #pragma unroll
            for (int e = 0; e < 8; ++e) acc[k * 8 + e] += bf2f(t[e]);
        }
    }
    float inv = 1.f / L;
    float* dst = out + ((size_t)(b * T_ + qt * 64 + row)) * HD_ + cg;
    #pragma unroll
    for (int k = 0; k < 8; ++k) {
        float4 o;
        o.x = acc[k * 4 + 0] * inv; o.y = acc[k * 4 + 1] * inv;
        o.z = acc[k * 4 + 2] * inv; o.w = acc[k * 4 + 3] * inv;
        *(float4*)(dst + k * 4) = o;
    }
}

extern "C" void kernel_launch(void* const* d_in, const int* in_sizes, int n_in,
                              void* d_out, int out_size, void* d_ws, size_t ws_size,
                              hipStream_t stream) {
    const float* x    = (const float*)d_in[0];
    const float* Wq   = (const float*)d_in[1];
    const float* Wk   = (const float*)d_in[2];
    const float* Wv   = (const float*)d_in[3];
    const float* cosp = (const float*)d_in[4];
    const float* sinp = (const float*)d_in[5];
    float* out = (float*)d_out;

    unsigned short* qws = (unsigned short*)d_ws;              // 4 MB
    unsigned short* kws = qws + (size_t)M_ * HD_;             // 4 MB
    unsigned short* vws = kws + (size_t)M_ * HD_;             // (B,128,T) 4 MB
    unsigned short* wbf = vws + (size_t)M_ * HD_;             // 1.5 MB
    unsigned short* partO = wbf + (size_t)3 * HD_ * C_;       // 1152*8192 u16 = 18.9 MB
    float* partL = (float*)(partO + (size_t)1152 * 64 * 128); // 1152*64 f32

    wconv<<<dim3(384), dim3(256), 0, stream>>>(Wq, Wk, Wv, wbf);
    qkv_gemm<<<dim3(768), dim3(256), 0, stream>>>(x, wbf, cosp, sinp, qws, kws, vws);
    attn_part<<<dim3(1152), dim3(256), 0, stream>>>(qws, kws, vws, partO, partL);
    attn_merge<<<dim3(256), dim3(256), 0, stream>>>(partO, partL, out);
}

// Round 9
// 281.694 us; speedup vs baseline: 1.1622x; 1.1622x over previous
//
#include <hip/hip_runtime.h>

#define B_ 4
#define T_ 4096
#define C_ 2048
#define HD_ 128
#define M_ (B_*T_)   // 16384 rows total

typedef __bf16 bf8 __attribute__((ext_vector_type(8)));
typedef __bf16 bf16x2 __attribute__((ext_vector_type(2)));
typedef __bf16 bf16x4 __attribute__((ext_vector_type(4)));
typedef unsigned short u16x8 __attribute__((ext_vector_type(8)));
typedef unsigned short u16x4 __attribute__((ext_vector_type(4)));
typedef float f32x4 __attribute__((ext_vector_type(4)));

typedef __attribute__((address_space(3))) unsigned char lds_u8_t;
typedef __attribute__((address_space(1))) const unsigned char gm_u8_t;

// async global->LDS, 16B per lane; LDS dest = wave-uniform base + lane*16
__device__ __forceinline__ void glds16(const void* g, void* l) {
    __builtin_amdgcn_global_load_lds((gm_u8_t*)g, (lds_u8_t*)l, 16, 0, 0);
}

// hardware bf16 conversion (gfx950: v_cvt_pk_bf16_f32), RNE
__device__ __forceinline__ bf8 cvt_bf8(float4 a, float4 b) {
    bf8 t;
    t[0]=(__bf16)a.x; t[1]=(__bf16)a.y; t[2]=(__bf16)a.z; t[3]=(__bf16)a.w;
    t[4]=(__bf16)b.x; t[5]=(__bf16)b.y; t[6]=(__bf16)b.z; t[7]=(__bf16)b.w;
    return t;
}
__device__ __forceinline__ unsigned pk2(float a, float b) {
    bf16x2 t; t[0] = (__bf16)a; t[1] = (__bf16)b;
    return __builtin_bit_cast(unsigned, t);
}
__device__ __forceinline__ u16x4 pk4(float a, float b, float c, float d) {
    bf16x4 t; t[0]=(__bf16)a; t[1]=(__bf16)b; t[2]=(__bf16)c; t[3]=(__bf16)d;
    return __builtin_bit_cast(u16x4, t);
}
__device__ __forceinline__ bf8 ld_bf8(const unsigned short* p) {
    u16x8 t = *(const u16x8*)p;
    return __builtin_bit_cast(bf8, t);
}
__device__ __forceinline__ float bf2f(unsigned short h) {
    unsigned u = ((unsigned)h) << 16;
    return __builtin_bit_cast(float, u);
}
__device__ __forceinline__ f32x4 zero4() { f32x4 v = {0.f,0.f,0.f,0.f}; return v; }

// ---------------------------------------------------------------------------
// Kernel 0: convert Wq|Wk|Wv (fp32) -> wbf (bf16), contiguous [3][128][2048]
// ---------------------------------------------------------------------------
__global__ __launch_bounds__(256) void wconv(
    const float* __restrict__ Wq, const float* __restrict__ Wk,
    const float* __restrict__ Wv, unsigned short* __restrict__ wbf)
{
    int idx = blockIdx.x * 256 + threadIdx.x;   // 0..98303
    int e = idx * 8;
    int z = e >> 18;                            // 128*2048 = 262144 = 2^18
    int r = e & 262143;
    const float* src = (z == 0 ? Wq : z == 1 ? Wk : Wv) + r;
    float4 a = *(const float4*)src;
    float4 b = *(const float4*)(src + 4);
    bf8 o = cvt_bf8(a, b);
    *(u16x8*)(wbf + e) = __builtin_bit_cast(u16x8, o);
}

// ---------------------------------------------------------------------------
// Kernel 1: per-matrix GEMM (x @ Wz^T) + RoPE epilogue — r7 version verbatim
// (best measured: 87 µs). Single-buffered 32 KB LDS, 3 blocks/CU, XCD-aware
// decode, HW bf16 casts. q pre-scaled by C^-0.5 * log2(e).
// NOTE: explicit double-buffering regressed TWICE (r3, r8) — occupancy loss
// beats drain gain. Keep single-buffered at >=3 blocks/CU.
// ---------------------------------------------------------------------------
__global__ __launch_bounds__(256) void qkv_gemm(
    const float* __restrict__ x, const unsigned short* __restrict__ wbf,
    const float* __restrict__ cosp, const float* __restrict__ sinp,
    unsigned short* __restrict__ qws, unsigned short* __restrict__ kws,
    unsigned short* __restrict__ vws)
{
    __shared__ __align__(16) float xs[64*64];            // 16 KB, [row][64 f32]
    __shared__ __align__(16) unsigned short ws2[128*64]; // 16 KB, [row][64 bf16]

    const int tid = threadIdx.x;
    const int w = tid >> 6, l = tid & 63;
    const int g = blockIdx.x;
    const int xcd = g & 7;
    const int s = g >> 3;            // 0..95
    const int z = s % 3;
    const int mm = s / 3;            // 0..31
    const int mt = mm * 8 + xcd;
    const int rowbase = mt * 64;

    const int swz = l & 7;
    const int aq  = l >> 4;
    const int coll = l & 15;

    f32x4 acc[2][4];
    #pragma unroll
    for (int i = 0; i < 2; ++i)
        #pragma unroll
        for (int j = 0; j < 4; ++j) acc[i][j] = zero4();

    const unsigned short* wsrc = wbf + (size_t)z * (HD_ * C_);

    for (int kc = 0; kc < C_; kc += 64) {
        __syncthreads();
        // stage x tile: 64 rows x 64 f32 (16 calls, 4/wave), fetch swizzled
        #pragma unroll
        for (int c = 0; c < 4; ++c) {
            int row = w * 16 + c * 4 + aq;
            int fb = coll ^ (row & 7);
            glds16(x + (size_t)(rowbase + row) * C_ + kc + fb * 4,
                   (void*)&xs[(w * 16 + c * 4) * 64]);
        }
        // stage W tile: 128 rows x 64 bf16 (16 calls, 4/wave)
        #pragma unroll
        for (int c = 0; c < 4; ++c) {
            int row = w * 32 + c * 8 + (l >> 3);
            int fb = (l & 7) ^ (row & 7);
            glds16(wsrc + (size_t)row * C_ + kc + fb * 8,
                   (void*)&ws2[(w * 32 + c * 8) * 64]);
        }
        __syncthreads();

        #pragma unroll
        for (int ks_ = 0; ks_ < 2; ++ks_) {
            bf8 a[2];
            #pragma unroll
            for (int mi = 0; mi < 2; ++mi) {
                int row = (w & 1) * 32 + mi * 16 + coll;   // row&7 == swz
                int s0 = ks_ * 8 + aq * 2;
                float4 fa = *(const float4*)&xs[row * 64 + ((s0 ^ swz) << 2)];
                float4 fb = *(const float4*)&xs[row * 64 + (((s0 + 1) ^ swz) << 2)];
                a[mi] = cvt_bf8(fa, fb);                   // HW v_cvt_pk_bf16_f32
            }
            #pragma unroll
            for (int nt = 0; nt < 4; ++nt) {
                int row = (w >> 1) * 64 + nt * 16 + coll;  // row&7 == swz
                int slot = (ks_ * 4 + aq) ^ swz;
                bf8 bb = ld_bf8(&ws2[row * 64 + (slot << 3)]);
                acc[0][nt] = __builtin_amdgcn_mfma_f32_16x16x32_bf16(a[0], bb, acc[0][nt], 0, 0, 0);
                acc[1][nt] = __builtin_amdgcn_mfma_f32_16x16x32_bf16(a[1], bb, acc[1][nt], 0, 0, 0);
            }
        }
    }

    // epilogue
    const int rl0 = aq * 4;
    const int cbase = (w >> 1) * 64;
    const int mrow = (w & 1) * 32;
    if (z < 2) {
        const float QSC = 0.022097086912079608f * 1.44269504088896340736f;
        const float fs = (z == 0) ? QSC : 1.0f;
        unsigned short* dst = (z == 0) ? qws : kws;
        #pragma unroll
        for (int mi = 0; mi < 2; ++mi) {
            #pragma unroll
            for (int nt = 0; nt < 4; ++nt) {
                int col = cbase + nt * 16 + coll;
                #pragma unroll
                for (int r = 0; r < 4; ++r) {
                    float val = acc[mi][nt][r];
                    float oth = __shfl_xor(val, 1, 64);
                    int grow = rowbase + mrow + mi * 16 + rl0 + r;
                    int t = grow & (T_ - 1);
                    if ((coll & 1) == 0) {
                        int i = col >> 1;
                        float cv = cosp[t * 64 + i], sv = sinp[t * 64 + i];
                        float o_r = (val * cv - oth * sv) * fs;
                        float o_i = (val * sv + oth * cv) * fs;
                        *(unsigned*)&dst[(size_t)grow * HD_ + col] = pk2(o_r, o_i);
                    }
                }
            }
        }
    } else {
        const int bq = rowbase >> 12;
        #pragma unroll
        for (int mi = 0; mi < 2; ++mi) {
            int tb = (rowbase + mrow + mi * 16 + rl0) & (T_ - 1);
            #pragma unroll
            for (int nt = 0; nt < 4; ++nt) {
                int col = cbase + nt * 16 + coll;
                u16x4 pk = pk4(acc[mi][nt][0], acc[mi][nt][1], acc[mi][nt][2], acc[mi][nt][3]);
                *(u16x4*)&vws[(size_t)(bq * HD_ + col) * T_ + tb] = pk;  // transposed
            }
        }
    }
}

// ---------------------------------------------------------------------------
// Kernel 2a: split-K causal flash attention, phase 1.
// Grid 1152 = 4 b x 288 jobs (<=8 K-tiles, r4/r8's proven decode, heavy-first,
// XCD-paired b). 64-row Q tiles; wave owns 16 rows x all 64 S-cols.
// SINGLE-buffered K/V staging (41 KB LDS -> 3 blocks/CU), 2 barriers/iter.
// Q in registers; wave-private P (no third barrier); fixed-max softmax
// (max==0; scores tiny) -> partials share max -> merge = plain sums.
// ---------------------------------------------------------------------------
__global__ __launch_bounds__(256) void attn_part(
    const unsigned short* __restrict__ qws, const unsigned short* __restrict__ kws,
    const unsigned short* __restrict__ vws,
    unsigned short* __restrict__ partO, float* __restrict__ partL)
{
    __shared__ __align__(16) unsigned short ks[64*128];   // 16 KB
    __shared__ __align__(16) unsigned short vs[128*64];   // 16 KB
    __shared__ __align__(16) unsigned short ps[4*16*72];  //  9 KB (per-wave P)

    const int tid = threadIdx.x;
    const int w = tid >> 6, l = tid & 63;
    // decode: XCD-paired b, heavy (8-tile) jobs first
    const int id = blockIdx.x;
    const int xcd = id & 7;
    const int b = xcd >> 1;
    const int j = (id >> 3) * 2 + (xcd & 1);    // 0..287
    const int sp = 287 - j;
    int g = 0;
    while (4 * (g + 1) * (g + 2) <= sp) ++g;
    const int r_ = sp - 4 * g * (g + 1);
    const int qdiv = r_ / (g + 1);
    const int qt = 8 * g + qdiv;                // 0..63
    const int c  = r_ - qdiv * (g + 1);         // chunk 0..g
    const int ntiles = (c < g) ? 8 : ((qt & 7) + 1);
    const int slot = b * 288 + 4 * g * (g + 1) + (qt & 7) * (g + 1) + c;
    const int qbase = qt * 64;
    const int cbase = c * 512;
    const size_t rowoff = (size_t)b * T_;

    const int swz = l & 7, aq = l >> 4, coll = l & 15;
    unsigned short* psw = ps + w * (16 * 72);

    // Q A-fragments in registers: A[m=coll][k = kk*32 + aq*8 + jj]
    bf8 qf[4];
    {
        const unsigned short* qp = qws + (rowoff + qbase + w * 16 + coll) * HD_ + aq * 8;
        #pragma unroll
        for (int kk = 0; kk < 4; ++kk) qf[kk] = ld_bf8(qp + kk * 32);
    }

    float l_r[4] = {0.f, 0.f, 0.f, 0.f};
    f32x4 accO[8];
    #pragma unroll
    for (int i = 0; i < 8; ++i) accO[i] = zero4();

    for (int st = 0; st < ntiles; ++st) {
        const int sbase = cbase + st * 64;
        __syncthreads();                              // prior-iter LDS reads done
        #pragma unroll
        for (int cc = 0; cc < 4; ++cc) {              // K: 64 rows x 128
            int row = w * 16 + cc * 4 + aq;
            int fb = coll ^ (row & 7);
            glds16(kws + (rowoff + sbase + row) * HD_ + fb * 8,
                   (void*)&ks[(w * 16 + cc * 4) * 128]);
        }
        #pragma unroll
        for (int cc = 0; cc < 4; ++cc) {              // V: 128 d-rows x 64 s
            int row = w * 32 + cc * 8 + (l >> 3);
            int fb = (l & 7) ^ (row & 7);
            glds16(vws + ((size_t)(b * HD_ + row)) * T_ + sbase + fb * 8,
                   (void*)&vs[(w * 32 + cc * 8) * 64]);
        }
        __syncthreads();                              // staging visible

        const bool masked = (sbase == qbase);         // only last tile of last chunk

        // S = Q K^T (wave: its 16 rows x 64 cols), Q from registers
        f32x4 sacc[4];
        #pragma unroll
        for (int i = 0; i < 4; ++i) sacc[i] = zero4();
        #pragma unroll
        for (int kk = 0; kk < 4; ++kk) {
            const int slot8 = ((kk * 4 + aq) ^ swz) << 3;
            #pragma unroll
            for (int nt = 0; nt < 4; ++nt) {
                bf8 bb = ld_bf8(&ks[(nt * 16 + coll) * 128 + slot8]);
                sacc[nt] = __builtin_amdgcn_mfma_f32_16x16x32_bf16(qf[kk], bb, sacc[nt], 0, 0, 0);
            }
        }

        // fixed-max softmax: p = exp2(s); wave-private ps; lane-local l
        #pragma unroll
        for (int r = 0; r < 4; ++r) {
            float s0 = sacc[0][r], s1 = sacc[1][r], s2 = sacc[2][r], s3 = sacc[3][r];
            if (masked) {
                int qi = qbase + w * 16 + aq * 4 + r;
                int ki = sbase + coll;
                s0 = (ki      > qi) ? -1e30f : s0;
                s1 = (ki + 16 > qi) ? -1e30f : s1;
                s2 = (ki + 32 > qi) ? -1e30f : s2;
                s3 = (ki + 48 > qi) ? -1e30f : s3;
            }
            float p0 = __builtin_amdgcn_exp2f(s0);
            float p1 = __builtin_amdgcn_exp2f(s1);
            float p2 = __builtin_amdgcn_exp2f(s2);
            float p3 = __builtin_amdgcn_exp2f(s3);
            __bf16 c0 = (__bf16)p0, c1 = (__bf16)p1, c2 = (__bf16)p2, c3 = (__bf16)p3;
            const int prow = (aq * 4 + r) * 72;
            psw[prow + coll]      = __builtin_bit_cast(unsigned short, c0);
            psw[prow + 16 + coll] = __builtin_bit_cast(unsigned short, c1);
            psw[prow + 32 + coll] = __builtin_bit_cast(unsigned short, c2);
            psw[prow + 48 + coll] = __builtin_bit_cast(unsigned short, c3);
            l_r[r] += ((float)c0 + (float)c1) + ((float)c2 + (float)c3);
        }
        // no barrier: ps is wave-private (same-wave LDS ordering)

        // O += P V (wave: 16 rows x 128 O-cols)
        #pragma unroll
        for (int kk = 0; kk < 2; ++kk) {
            bf8 a = ld_bf8(&psw[coll * 72 + kk * 32 + aq * 8]);
            const int slot8 = ((kk * 4 + aq) ^ swz) << 3;
            #pragma unroll
            for (int nt = 0; nt < 8; ++nt) {
                bf8 bb = ld_bf8(&vs[(nt * 16 + coll) * 64 + slot8]);
                accO[nt] = __builtin_amdgcn_mfma_f32_16x16x32_bf16(a, bb, accO[nt], 0, 0, 0);
            }
        }
    }

    // epilogue: unnormalized bf16 O + fp32 l per row (shared max==0)
    unsigned short* op = partO + (size_t)slot * (64 * 128);
    #pragma unroll
    for (int r = 0; r < 4; ++r) {
        float s = l_r[r];
        s += __shfl_xor(s, 1, 64);
        s += __shfl_xor(s, 2, 64);
        s += __shfl_xor(s, 4, 64);
        s += __shfl_xor(s, 8, 64);
        int row = w * 16 + aq * 4 + r;
        #pragma unroll
        for (int nt = 0; nt < 8; ++nt) {
            __bf16 ob = (__bf16)accO[nt][r];
            op[row * 128 + nt * 16 + coll] = __builtin_bit_cast(unsigned short, ob);
        }
        if (coll == 0) partL[slot * 64 + row] = s;
    }
}

// ---------------------------------------------------------------------------
// Kernel 2b: merge partials (plain sums — shared fixed max). Grid 256 =
// (b,qt); thread owns one (row, 32-col group).
// ---------------------------------------------------------------------------
__global__ __launch_bounds__(256) void attn_merge(
    const unsigned short* __restrict__ partO, const float* __restrict__ partL,
    float* __restrict__ out)
{
    const int bq = blockIdx.x;
    const int b = bq >> 6, qt = bq & 63;
    const int g = qt >> 3;
    const int nc = g + 1;
    const int slotbase = b * 288 + 4 * g * (g + 1) + (qt & 7) * (g + 1);
    const int row = threadIdx.x >> 2;
    const int cg = (threadIdx.x & 3) * 32;

    float acc[32];
    #pragma unroll
    for (int e = 0; e < 32; ++e) acc[e] = 0.f;
    float L = 0.f;
    for (int c = 0; c < nc; ++c) {
        const int slot = slotbase + c;
        L += partL[slot * 64 + row];
        const unsigned short* op = partO + (size_t)slot * (64 * 128) + row * 128 + cg;
        #pragma unroll
        for (int k = 0; k < 4; ++k) {
            u16x8 t = *(const u16x8*)(op + k * 8);
            #pragma unroll
            for (int e = 0; e < 8; ++e) acc[k * 8 + e] += bf2f(t[e]);
        }
    }
    float inv = 1.f / L;
    float* dst = out + ((size_t)(b * T_ + qt * 64 + row)) * HD_ + cg;
    #pragma unroll
    for (int k = 0; k < 8; ++k) {
        float4 o;
        o.x = acc[k * 4 + 0] * inv; o.y = acc[k * 4 + 1] * inv;
        o.z = acc[k * 4 + 2] * inv; o.w = acc[k * 4 + 3] * inv;
        *(float4*)(dst + k * 4) = o;
    }
}

extern "C" void kernel_launch(void* const* d_in, const int* in_sizes, int n_in,
                              void* d_out, int out_size, void* d_ws, size_t ws_size,
                              hipStream_t stream) {
    const float* x    = (const float*)d_in[0];
    const float* Wq   = (const float*)d_in[1];
    const float* Wk   = (const float*)d_in[2];
    const float* Wv   = (const float*)d_in[3];
    const float* cosp = (const float*)d_in[4];
    const float* sinp = (const float*)d_in[5];
    float* out = (float*)d_out;

    unsigned short* qws = (unsigned short*)d_ws;              // 4 MB
    unsigned short* kws = qws + (size_t)M_ * HD_;             // 4 MB
    unsigned short* vws = kws + (size_t)M_ * HD_;             // (B,128,T) 4 MB
    unsigned short* wbf = vws + (size_t)M_ * HD_;             // 1.5 MB
    unsigned short* partO = wbf + (size_t)3 * HD_ * C_;       // 1152*8192 u16 = 18.9 MB
    float* partL = (float*)(partO + (size_t)1152 * 64 * 128); // 1152*64 f32

    wconv<<<dim3(384), dim3(256), 0, stream>>>(Wq, Wk, Wv, wbf);
    qkv_gemm<<<dim3(768), dim3(256), 0, stream>>>(x, wbf, cosp, sinp, qws, kws, vws);
    attn_part<<<dim3(1152), dim3(256), 0, stream>>>(qws, kws, vws, partO, partL);
    attn_merge<<<dim3(256), dim3(256), 0, stream>>>(partO, partL, out);
}

// Round 10
// 280.174 us; speedup vs baseline: 1.1685x; 1.0054x over previous
//
#include <hip/hip_runtime.h>

#define B_ 4
#define T_ 4096
#define C_ 2048
#define HD_ 128
#define M_ (B_*T_)   // 16384 rows total

typedef __bf16 bf8 __attribute__((ext_vector_type(8)));
typedef __bf16 bf16x2 __attribute__((ext_vector_type(2)));
typedef __bf16 bf16x4 __attribute__((ext_vector_type(4)));
typedef unsigned short u16x8 __attribute__((ext_vector_type(8)));
typedef unsigned short u16x4 __attribute__((ext_vector_type(4)));
typedef float f32x4 __attribute__((ext_vector_type(4)));

typedef __attribute__((address_space(3))) unsigned char lds_u8_t;
typedef __attribute__((address_space(1))) const unsigned char gm_u8_t;

// async global->LDS, 16B per lane; LDS dest = wave-uniform base + lane*16
__device__ __forceinline__ void glds16(const void* g, void* l) {
    __builtin_amdgcn_global_load_lds((gm_u8_t*)g, (lds_u8_t*)l, 16, 0, 0);
}

// hardware bf16 conversion (gfx950: v_cvt_pk_bf16_f32), RNE
__device__ __forceinline__ bf8 cvt_bf8(float4 a, float4 b) {
    bf8 t;
    t[0]=(__bf16)a.x; t[1]=(__bf16)a.y; t[2]=(__bf16)a.z; t[3]=(__bf16)a.w;
    t[4]=(__bf16)b.x; t[5]=(__bf16)b.y; t[6]=(__bf16)b.z; t[7]=(__bf16)b.w;
    return t;
}
__device__ __forceinline__ unsigned pk2(float a, float b) {
    bf16x2 t; t[0] = (__bf16)a; t[1] = (__bf16)b;
    return __builtin_bit_cast(unsigned, t);
}
__device__ __forceinline__ u16x4 pk4(float a, float b, float c, float d) {
    bf16x4 t; t[0]=(__bf16)a; t[1]=(__bf16)b; t[2]=(__bf16)c; t[3]=(__bf16)d;
    return __builtin_bit_cast(u16x4, t);
}
__device__ __forceinline__ bf8 ld_bf8(const unsigned short* p) {
    u16x8 t = *(const u16x8*)p;
    return __builtin_bit_cast(bf8, t);
}
__device__ __forceinline__ float bf2f(unsigned short h) {
    unsigned u = ((unsigned)h) << 16;
    return __builtin_bit_cast(float, u);
}
__device__ __forceinline__ f32x4 zero4() { f32x4 v = {0.f,0.f,0.f,0.f}; return v; }

// ---------------------------------------------------------------------------
// Kernel 0: convert Wq|Wk|Wv (fp32) -> wbf (bf16), contiguous [3][128][2048]
// ---------------------------------------------------------------------------
__global__ __launch_bounds__(256) void wconv(
    const float* __restrict__ Wq, const float* __restrict__ Wk,
    const float* __restrict__ Wv, unsigned short* __restrict__ wbf)
{
    int idx = blockIdx.x * 256 + threadIdx.x;   // 0..98303
    int e = idx * 8;
    int z = e >> 18;                            // 128*2048 = 262144 = 2^18
    int r = e & 262143;
    const float* src = (z == 0 ? Wq : z == 1 ? Wk : Wv) + r;
    float4 a = *(const float4*)src;
    float4 b = *(const float4*)(src + 4);
    bf8 o = cvt_bf8(a, b);
    *(u16x8*)(wbf + e) = __builtin_bit_cast(u16x8, o);
}

// ---------------------------------------------------------------------------
// Kernel 1: per-matrix GEMM (x @ Wz^T) + RoPE epilogue — r7 version verbatim
// (best measured: 87 µs; pinned there across 4 structural variants).
// Single-buffered 32 KB LDS, 3 blocks/CU, XCD-aware decode, HW bf16 casts.
// q pre-scaled by C^-0.5 * log2(e).
// ---------------------------------------------------------------------------
__global__ __launch_bounds__(256) void qkv_gemm(
    const float* __restrict__ x, const unsigned short* __restrict__ wbf,
    const float* __restrict__ cosp, const float* __restrict__ sinp,
    unsigned short* __restrict__ qws, unsigned short* __restrict__ kws,
    unsigned short* __restrict__ vws)
{
    __shared__ __align__(16) float xs[64*64];            // 16 KB, [row][64 f32]
    __shared__ __align__(16) unsigned short ws2[128*64]; // 16 KB, [row][64 bf16]

    const int tid = threadIdx.x;
    const int w = tid >> 6, l = tid & 63;
    const int g = blockIdx.x;
    const int xcd = g & 7;
    const int s = g >> 3;            // 0..95
    const int z = s % 3;
    const int mm = s / 3;            // 0..31
    const int mt = mm * 8 + xcd;
    const int rowbase = mt * 64;

    const int swz = l & 7;
    const int aq  = l >> 4;
    const int coll = l & 15;

    f32x4 acc[2][4];
    #pragma unroll
    for (int i = 0; i < 2; ++i)
        #pragma unroll
        for (int j = 0; j < 4; ++j) acc[i][j] = zero4();

    const unsigned short* wsrc = wbf + (size_t)z * (HD_ * C_);

    for (int kc = 0; kc < C_; kc += 64) {
        __syncthreads();
        // stage x tile: 64 rows x 64 f32 (16 calls, 4/wave), fetch swizzled
        #pragma unroll
        for (int c = 0; c < 4; ++c) {
            int row = w * 16 + c * 4 + aq;
            int fb = coll ^ (row & 7);
            glds16(x + (size_t)(rowbase + row) * C_ + kc + fb * 4,
                   (void*)&xs[(w * 16 + c * 4) * 64]);
        }
        // stage W tile: 128 rows x 64 bf16 (16 calls, 4/wave)
        #pragma unroll
        for (int c = 0; c < 4; ++c) {
            int row = w * 32 + c * 8 + (l >> 3);
            int fb = (l & 7) ^ (row & 7);
            glds16(wsrc + (size_t)row * C_ + kc + fb * 8,
                   (void*)&ws2[(w * 32 + c * 8) * 64]);
        }
        __syncthreads();

        #pragma unroll
        for (int ks_ = 0; ks_ < 2; ++ks_) {
            bf8 a[2];
            #pragma unroll
            for (int mi = 0; mi < 2; ++mi) {
                int row = (w & 1) * 32 + mi * 16 + coll;   // row&7 == swz
                int s0 = ks_ * 8 + aq * 2;
                float4 fa = *(const float4*)&xs[row * 64 + ((s0 ^ swz) << 2)];
                float4 fb = *(const float4*)&xs[row * 64 + (((s0 + 1) ^ swz) << 2)];
                a[mi] = cvt_bf8(fa, fb);                   // HW v_cvt_pk_bf16_f32
            }
            #pragma unroll
            for (int nt = 0; nt < 4; ++nt) {
                int row = (w >> 1) * 64 + nt * 16 + coll;  // row&7 == swz
                int slot = (ks_ * 4 + aq) ^ swz;
                bf8 bb = ld_bf8(&ws2[row * 64 + (slot << 3)]);
                acc[0][nt] = __builtin_amdgcn_mfma_f32_16x16x32_bf16(a[0], bb, acc[0][nt], 0, 0, 0);
                acc[1][nt] = __builtin_amdgcn_mfma_f32_16x16x32_bf16(a[1], bb, acc[1][nt], 0, 0, 0);
            }
        }
    }

    // epilogue
    const int rl0 = aq * 4;
    const int cbase = (w >> 1) * 64;
    const int mrow = (w & 1) * 32;
    if (z < 2) {
        const float QSC = 0.022097086912079608f * 1.44269504088896340736f;
        const float fs = (z == 0) ? QSC : 1.0f;
        unsigned short* dst = (z == 0) ? qws : kws;
        #pragma unroll
        for (int mi = 0; mi < 2; ++mi) {
            #pragma unroll
            for (int nt = 0; nt < 4; ++nt) {
                int col = cbase + nt * 16 + coll;
                #pragma unroll
                for (int r = 0; r < 4; ++r) {
                    float val = acc[mi][nt][r];
                    float oth = __shfl_xor(val, 1, 64);
                    int grow = rowbase + mrow + mi * 16 + rl0 + r;
                    int t = grow & (T_ - 1);
                    if ((coll & 1) == 0) {
                        int i = col >> 1;
                        float cv = cosp[t * 64 + i], sv = sinp[t * 64 + i];
                        float o_r = (val * cv - oth * sv) * fs;
                        float o_i = (val * sv + oth * cv) * fs;
                        *(unsigned*)&dst[(size_t)grow * HD_ + col] = pk2(o_r, o_i);
                    }
                }
            }
        }
    } else {
        const int bq = rowbase >> 12;
        #pragma unroll
        for (int mi = 0; mi < 2; ++mi) {
            int tb = (rowbase + mrow + mi * 16 + rl0) & (T_ - 1);
            #pragma unroll
            for (int nt = 0; nt < 4; ++nt) {
                int col = cbase + nt * 16 + coll;
                u16x4 pk = pk4(acc[mi][nt][0], acc[mi][nt][1], acc[mi][nt][2], acc[mi][nt][3]);
                *(u16x4*)&vws[(size_t)(bq * HD_ + col) * T_ + tb] = pk;  // transposed
            }
        }
    }
}

// ---------------------------------------------------------------------------
// Kernel 2a: split-K causal flash attention, phase 1.
// Grid 1152 = 4 b x 288 jobs (<=8 K-tiles, heavy-first, XCD-paired b).
// 64-row Q tiles; wave owns 16 rows x all 64 S-cols. SINGLE-buffered K/V
// (41 KB LDS -> 3 blocks/CU), 2 barriers/iter, Q in registers, wave-private P.
// Fixed-max softmax (max==0). NEW: denominator computed by an extra MFMA
// against a ones B-fragment (l = P @ 1) — removes all denominator VALU ops
// from the softmax chain AND the epilogue shfl reduction; result is
// bit-identical to summing the bf16 P values (same A-register operand).
// ---------------------------------------------------------------------------
__global__ __launch_bounds__(256) void attn_part(
    const unsigned short* __restrict__ qws, const unsigned short* __restrict__ kws,
    const unsigned short* __restrict__ vws,
    unsigned short* __restrict__ partO, float* __restrict__ partL)
{
    __shared__ __align__(16) unsigned short ks[64*128];   // 16 KB
    __shared__ __align__(16) unsigned short vs[128*64];   // 16 KB
    __shared__ __align__(16) unsigned short ps[4*16*72];  //  9 KB (per-wave P)

    const int tid = threadIdx.x;
    const int w = tid >> 6, l = tid & 63;
    // decode: XCD-paired b, heavy (8-tile) jobs first
    const int id = blockIdx.x;
    const int xcd = id & 7;
    const int b = xcd >> 1;
    const int j = (id >> 3) * 2 + (xcd & 1);    // 0..287
    const int sp = 287 - j;
    int g = 0;
    while (4 * (g + 1) * (g + 2) <= sp) ++g;
    const int r_ = sp - 4 * g * (g + 1);
    const int qdiv = r_ / (g + 1);
    const int qt = 8 * g + qdiv;                // 0..63
    const int c  = r_ - qdiv * (g + 1);         // chunk 0..g
    const int ntiles = (c < g) ? 8 : ((qt & 7) + 1);
    const int slot = b * 288 + 4 * g * (g + 1) + (qt & 7) * (g + 1) + c;
    const int qbase = qt * 64;
    const int cbase = c * 512;
    const size_t rowoff = (size_t)b * T_;

    const int swz = l & 7, aq = l >> 4, coll = l & 15;
    unsigned short* psw = ps + w * (16 * 72);

    // ones B-fragment for the denominator MFMA
    bf8 ones;
    #pragma unroll
    for (int e = 0; e < 8; ++e) ones[e] = (__bf16)1.0f;

    // Q A-fragments in registers: A[m=coll][k = kk*32 + aq*8 + jj]
    bf8 qf[4];
    {
        const unsigned short* qp = qws + (rowoff + qbase + w * 16 + coll) * HD_ + aq * 8;
        #pragma unroll
        for (int kk = 0; kk < 4; ++kk) qf[kk] = ld_bf8(qp + kk * 32);
    }

    f32x4 accO[8];
    #pragma unroll
    for (int i = 0; i < 8; ++i) accO[i] = zero4();
    f32x4 accL = zero4();   // row-sums of P (denominator), via ones-MFMA

    for (int st = 0; st < ntiles; ++st) {
        const int sbase = cbase + st * 64;
        __syncthreads();                              // prior-iter LDS reads done
        #pragma unroll
        for (int cc = 0; cc < 4; ++cc) {              // K: 64 rows x 128
            int row = w * 16 + cc * 4 + aq;
            int fb = coll ^ (row & 7);
            glds16(kws + (rowoff + sbase + row) * HD_ + fb * 8,
                   (void*)&ks[(w * 16 + cc * 4) * 128]);
        }
        #pragma unroll
        for (int cc = 0; cc < 4; ++cc) {              // V: 128 d-rows x 64 s
            int row = w * 32 + cc * 8 + (l >> 3);
            int fb = (l & 7) ^ (row & 7);
            glds16(vws + ((size_t)(b * HD_ + row)) * T_ + sbase + fb * 8,
                   (void*)&vs[(w * 32 + cc * 8) * 64]);
        }
        __syncthreads();                              // staging visible

        const bool masked = (sbase == qbase);         // only last tile of last chunk

        // S = Q K^T (wave: its 16 rows x 64 cols), Q from registers
        f32x4 sacc[4];
        #pragma unroll
        for (int i = 0; i < 4; ++i) sacc[i] = zero4();
        #pragma unroll
        for (int kk = 0; kk < 4; ++kk) {
            const int slot8 = ((kk * 4 + aq) ^ swz) << 3;
            #pragma unroll
            for (int nt = 0; nt < 4; ++nt) {
                bf8 bb = ld_bf8(&ks[(nt * 16 + coll) * 128 + slot8]);
                sacc[nt] = __builtin_amdgcn_mfma_f32_16x16x32_bf16(qf[kk], bb, sacc[nt], 0, 0, 0);
            }
        }

        // fixed-max softmax: p = exp2(s); wave-private ps; no denominator VALU
        #pragma unroll
        for (int r = 0; r < 4; ++r) {
            float s0 = sacc[0][r], s1 = sacc[1][r], s2 = sacc[2][r], s3 = sacc[3][r];
            if (masked) {
                int qi = qbase + w * 16 + aq * 4 + r;
                int ki = sbase + coll;
                s0 = (ki      > qi) ? -1e30f : s0;
                s1 = (ki + 16 > qi) ? -1e30f : s1;
                s2 = (ki + 32 > qi) ? -1e30f : s2;
                s3 = (ki + 48 > qi) ? -1e30f : s3;
            }
            float p0 = __builtin_amdgcn_exp2f(s0);
            float p1 = __builtin_amdgcn_exp2f(s1);
            float p2 = __builtin_amdgcn_exp2f(s2);
            float p3 = __builtin_amdgcn_exp2f(s3);
            const int prow = (aq * 4 + r) * 72;
            psw[prow + coll]      = __builtin_bit_cast(unsigned short, (__bf16)p0);
            psw[prow + 16 + coll] = __builtin_bit_cast(unsigned short, (__bf16)p1);
            psw[prow + 32 + coll] = __builtin_bit_cast(unsigned short, (__bf16)p2);
            psw[prow + 48 + coll] = __builtin_bit_cast(unsigned short, (__bf16)p3);
        }
        // no barrier: ps is wave-private (same-wave LDS ordering)

        // O += P V, and accL += P @ 1 (wave: 16 rows x 128 O-cols)
        #pragma unroll
        for (int kk = 0; kk < 2; ++kk) {
            bf8 a = ld_bf8(&psw[coll * 72 + kk * 32 + aq * 8]);
            accL = __builtin_amdgcn_mfma_f32_16x16x32_bf16(a, ones, accL, 0, 0, 0);
            const int slot8 = ((kk * 4 + aq) ^ swz) << 3;
            #pragma unroll
            for (int nt = 0; nt < 8; ++nt) {
                bf8 bb = ld_bf8(&vs[(nt * 16 + coll) * 64 + slot8]);
                accO[nt] = __builtin_amdgcn_mfma_f32_16x16x32_bf16(a, bb, accO[nt], 0, 0, 0);
            }
        }
    }

    // epilogue: unnormalized bf16 O + fp32 l per row (shared max==0).
    // accL row-sums are replicated across the 16 col-lanes -> no shfl needed.
    unsigned short* op = partO + (size_t)slot * (64 * 128);
    #pragma unroll
    for (int r = 0; r < 4; ++r) {
        int row = w * 16 + aq * 4 + r;
        #pragma unroll
        for (int nt = 0; nt < 8; ++nt) {
            __bf16 ob = (__bf16)accO[nt][r];
            op[row * 128 + nt * 16 + coll] = __builtin_bit_cast(unsigned short, ob);
        }
        if (coll == 0) partL[slot * 64 + row] = accL[r];
    }
}

// ---------------------------------------------------------------------------
// Kernel 2b: merge partials (plain sums — shared fixed max). Grid 256 =
// (b,qt); thread owns one (row, 32-col group).
// ---------------------------------------------------------------------------
__global__ __launch_bounds__(256) void attn_merge(
    const unsigned short* __restrict__ partO, const float* __restrict__ partL,
    float* __restrict__ out)
{
    const int bq = blockIdx.x;
    const int b = bq >> 6, qt = bq & 63;
    const int g = qt >> 3;
    const int nc = g + 1;
    const int slotbase = b * 288 + 4 * g * (g + 1) + (qt & 7) * (g + 1);
    const int row = threadIdx.x >> 2;
    const int cg = (threadIdx.x & 3) * 32;

    float acc[32];
    #pragma unroll
    for (int e = 0; e < 32; ++e) acc[e] = 0.f;
    float L = 0.f;
    for (int c = 0; c < nc; ++c) {
        const int slot = slotbase + c;
        L += partL[slot * 64 + row];
        const unsigned short* op = partO + (size_t)slot * (64 * 128) + row * 128 + cg;
        #pragma unroll
        for (int k = 0; k < 4; ++k) {
            u16x8 t = *(const u16x8*)(op + k * 8);
            #pragma unroll
            for (int e = 0; e < 8; ++e) acc[k * 8 + e] += bf2f(t[e]);
        }
    }
    float inv = 1.f / L;
    float* dst = out + ((size_t)(b * T_ + qt * 64 + row)) * HD_ + cg;
    #pragma unroll
    for (int k = 0; k < 8; ++k) {
        float4 o;
        o.x = acc[k * 4 + 0] * inv; o.y = acc[k * 4 + 1] * inv;
        o.z = acc[k * 4 + 2] * inv; o.w = acc[k * 4 + 3] * inv;
        *(float4*)(dst + k * 4) = o;
    }
}

extern "C" void kernel_launch(void* const* d_in, const int* in_sizes, int n_in,
                              void* d_out, int out_size, void* d_ws, size_t ws_size,
                              hipStream_t stream) {
    const float* x    = (const float*)d_in[0];
    const float* Wq   = (const float*)d_in[1];
    const float* Wk   = (const float*)d_in[2];
    const float* Wv   = (const float*)d_in[3];
    const float* cosp = (const float*)d_in[4];
    const float* sinp = (const float*)d_in[5];
    float* out = (float*)d_out;

    unsigned short* qws = (unsigned short*)d_ws;              // 4 MB
    unsigned short* kws = qws + (size_t)M_ * HD_;             // 4 MB
    unsigned short* vws = kws + (size_t)M_ * HD_;             // (B,128,T) 4 MB
    unsigned short* wbf = vws + (size_t)M_ * HD_;             // 1.5 MB
    unsigned short* partO = wbf + (size_t)3 * HD_ * C_;       // 1152*8192 u16 = 18.9 MB
    float* partL = (float*)(partO + (size_t)1152 * 64 * 128); // 1152*64 f32

    wconv<<<dim3(384), dim3(256), 0, stream>>>(Wq, Wk, Wv, wbf);
    qkv_gemm<<<dim3(768), dim3(256), 0, stream>>>(x, wbf, cosp, sinp, qws, kws, vws);
    attn_part<<<dim3(1152), dim3(256), 0, stream>>>(qws, kws, vws, partO, partL);
    attn_merge<<<dim3(256), dim3(256), 0, stream>>>(partO, partL, out);
}